// Round 3
// baseline (108.061 us; speedup 1.0000x reference)
//
#include <hip/hip_runtime.h>
#include <hip/hip_bf16.h>

#define B_   32
#define N_   2048
#define VD_  512
#define AD_  128
#define SD_  128
#define TM   128
#define THREADS 512

typedef __attribute__((ext_vector_type(8))) short short8;
typedef __attribute__((ext_vector_type(4))) float f32x4;

// ws layout (ushort element offsets) for pre-converted bf16 weights
#define WOFF_VFC 0        // [128][512]
#define WOFF_AFC 65536    // [128][128]
#define WOFF_AM  81920    // [128][128]
#define WOFF_V   98304    // [64][128]
#define WOFF_U   106496   // [64][128]
#define WTOT     114688   // ushorts = 229376 bytes; zpart follows

__device__ __forceinline__ float sigmoidf_(float x) { return 1.0f / (1.0f + __expf(-x)); }

__device__ __forceinline__ ushort f2bf(float x) {   // RNE
    union { float f; unsigned int i; } v; v.f = x;
    unsigned int r = v.i + 0x7FFFu + ((v.i >> 16) & 1u);
    return (ushort)(r >> 16);
}
__device__ __forceinline__ float bf2f(ushort u) {
    union { unsigned int i; float f; } v; v.i = ((unsigned int)u) << 16; return v.f;
}
// Swizzled elem index into row-major [R][ldk] ushort LDS tile (T2-style; keeps 16B chunks)
__device__ __forceinline__ int swz(int row, int k, int ldk) {
    return row * ldk + (k ^ ((row & 7) << 3));
}
__device__ __forceinline__ short8 cvt8(const float* p) {
    float4 x = ((const float4*)p)[0], y = ((const float4*)p)[1];
    short8 r;
    r[0] = (short)f2bf(x.x); r[1] = (short)f2bf(x.y); r[2] = (short)f2bf(x.z); r[3] = (short)f2bf(x.w);
    r[4] = (short)f2bf(y.x); r[5] = (short)f2bf(y.y); r[6] = (short)f2bf(y.z); r[7] = (short)f2bf(y.w);
    return r;
}

// ---- weight pre-conversion: f32 -> bf16 into ws (one tiny kernel, every call) ----
__global__ __launch_bounds__(256)
void cvt_weights(const float* __restrict__ vfc, const float* __restrict__ afc,
                 const float* __restrict__ am,  const float* __restrict__ Vw,
                 const float* __restrict__ Uw,  ushort* __restrict__ dst)
{
    int e = (blockIdx.x * 256 + threadIdx.x) * 4;
    if (e >= WTOT) return;
    const float* src; int off;
    if      (e < WOFF_AFC) { src = vfc; off = e - WOFF_VFC; }
    else if (e < WOFF_AM)  { src = afc; off = e - WOFF_AFC; }
    else if (e < WOFF_V)   { src = am;  off = e - WOFF_AM;  }
    else if (e < WOFF_U)   { src = Vw;  off = e - WOFF_V;   }
    else                   { src = Uw;  off = e - WOFF_U;   }
    float4 v = *(const float4*)(src + off);
    ushort4 o; o.x = f2bf(v.x); o.y = f2bf(v.y); o.z = f2bf(v.z); o.w = f2bf(v.w);
    *(ushort4*)(dst + e) = o;
}

// GEMM, A from global f32 (converted in-reg), B from global bf16. No LDS, no barriers.
// Wave (wr,wc) owns a 32x64 tile; out row = 32wr+16m+4g4+r, col = 64wc+16n+t16.
template<int K, int UNROLL>
__device__ __forceinline__ void gemm_gf(const float* __restrict__ A,      // [rows][K] at tile base
                                        const ushort* __restrict__ Bw,    // [128][K]
                                        int wr, int wc, int t16, int g4,
                                        f32x4 (&acc)[2][4])
{
    #pragma unroll UNROLL
    for (int ks = 0; ks < K; ks += 32) {
        int k = ks + g4 * 8;
        short8 a0 = cvt8(&A[(size_t)(32 * wr + t16) * K + k]);
        short8 a1 = cvt8(&A[(size_t)(32 * wr + 16 + t16) * K + k]);
        #pragma unroll
        for (int n = 0; n < 4; ++n) {
            short8 bf = *(const short8*)&Bw[(64 * wc + 16 * n + t16) * K + k];
            acc[0][n] = __builtin_amdgcn_mfma_f32_16x16x32_bf16(a0, bf, acc[0][n], 0, 0, 0);
            acc[1][n] = __builtin_amdgcn_mfma_f32_16x16x32_bf16(a1, bf, acc[1][n], 0, 0, 0);
        }
    }
}

// GEMM, A from swizzled LDS bf16, B from global bf16.
template<int K>
__device__ __forceinline__ void gemm_lf(const ushort* __restrict__ Ab,    // LDS [128][128] swz
                                        const ushort* __restrict__ Bw,    // [128][K]
                                        int wr, int wc, int t16, int g4,
                                        f32x4 (&acc)[2][4])
{
    #pragma unroll
    for (int ks = 0; ks < K; ks += 32) {
        int k = ks + g4 * 8;
        short8 a0 = *(const short8*)&Ab[swz(32 * wr + t16,      k, 128)];
        short8 a1 = *(const short8*)&Ab[swz(32 * wr + 16 + t16, k, 128)];
        #pragma unroll
        for (int n = 0; n < 4; ++n) {
            short8 bf = *(const short8*)&Bw[(64 * wc + 16 * n + t16) * K + k];
            acc[0][n] = __builtin_amdgcn_mfma_f32_16x16x32_bf16(a0, bf, acc[0][n], 0, 0, 0);
            acc[1][n] = __builtin_amdgcn_mfma_f32_16x16x32_bf16(a1, bf, acc[1][n], 0, 0, 0);
        }
    }
}

// Grid: 32 b x 16 tiles = 512 blocks, 512 threads (8 waves). LDS ~35.5KB -> 2 blocks/CU.
__global__ __launch_bounds__(THREADS, 4)
void fused_mil(const float* __restrict__ vfeat, const float* __restrict__ afeat,
               const ushort* __restrict__ wsW,
               const float* __restrict__ afc_b, const float* __restrict__ am_b,
               const float* __restrict__ vfc_b,
               const float* __restrict__ V_b,   const float* __restrict__ U_b,
               const float* __restrict__ W_w,   const float* __restrict__ W_b,
               float* __restrict__ s_out, float* __restrict__ zpart)
{
    __shared__ __align__(16) ushort Xbuf[128 * 128];  // ax -> gate -> ffeat (aliased)
    __shared__ float sP[2][128];
    __shared__ float sS[128];
    __shared__ float zq[4][128];

    const int tid  = threadIdx.x;
    const int bx   = blockIdx.x;
    const int b    = bx >> 4;
    const int tok0 = (bx & 15) * TM;
    const int wid  = tid >> 6;
    const int lane = tid & 63;
    const int t16  = lane & 15;
    const int g4   = lane >> 4;
    const int wr   = wid >> 1;
    const int wc   = wid & 1;

    f32x4 acc[2][4];

    // ---- Phase A: ax = relu(afeat @ afc_w^T + afc_b) -> Xbuf ----
    #pragma unroll
    for (int m = 0; m < 2; ++m)
        #pragma unroll
        for (int n = 0; n < 4; ++n) acc[m][n] = (f32x4)0.0f;
    gemm_gf<AD_, 4>(afeat + ((size_t)b * N_ + tok0) * AD_, wsW + WOFF_AFC, wr, wc, t16, g4, acc);
    #pragma unroll
    for (int n = 0; n < 4; ++n) {
        int c = 64 * wc + 16 * n + t16;
        float bias = afc_b[c];
        #pragma unroll
        for (int m = 0; m < 2; ++m)
            #pragma unroll
            for (int r = 0; r < 4; ++r) {
                int row = 32 * wr + 16 * m + 4 * g4 + r;
                Xbuf[swz(row, c, 128)] = f2bf(fmaxf(acc[m][n][r] + bias, 0.0f));
            }
    }
    __syncthreads();

    // ---- Phase B: gate = sigmoid(ax @ am_w^T + am_b), stashed bf16 into Xbuf ----
    #pragma unroll
    for (int m = 0; m < 2; ++m)
        #pragma unroll
        for (int n = 0; n < 4; ++n) acc[m][n] = (f32x4)0.0f;
    gemm_lf<SD_>(Xbuf, wsW + WOFF_AM, wr, wc, t16, g4, acc);
    __syncthreads();   // everyone done reading ax
    #pragma unroll
    for (int n = 0; n < 4; ++n) {
        int c = 64 * wc + 16 * n + t16;
        float bias = am_b[c];
        #pragma unroll
        for (int m = 0; m < 2; ++m)
            #pragma unroll
            for (int r = 0; r < 4; ++r) {
                int row = 32 * wr + 16 * m + 4 * g4 + r;
                Xbuf[swz(row, c, 128)] = f2bf(sigmoidf_(acc[m][n][r] + bias));
            }
    }
    // no barrier needed: phase C touches no LDS; gate cells are thread-private

    // ---- Phase C: vo1 = vfeat @ vfc_w^T  (K=512, barrier-free, deep pipeline) ----
    #pragma unroll
    for (int m = 0; m < 2; ++m)
        #pragma unroll
        for (int n = 0; n < 4; ++n) acc[m][n] = (f32x4)0.0f;
    gemm_gf<VD_, 4>(vfeat + ((size_t)b * N_ + tok0) * VD_, wsW + WOFF_VFC, wr, wc, t16, g4, acc);

    // epilogue: ffeat = relu(vo1+b) * (1 + gate) -> Xbuf (own cells: read gate, write ffeat)
    #pragma unroll
    for (int n = 0; n < 4; ++n) {
        int c = 64 * wc + 16 * n + t16;
        float vb = vfc_b[c];
        #pragma unroll
        for (int m = 0; m < 2; ++m)
            #pragma unroll
            for (int r = 0; r < 4; ++r) {
                int row = 32 * wr + 16 * m + 4 * g4 + r;
                float g   = bf2f(Xbuf[swz(row, c, 128)]);
                float vo1 = fmaxf(acc[m][n][r] + vb, 0.0f);
                Xbuf[swz(row, c, 128)] = f2bf(vo1 * (1.0f + g));
            }
    }
    __syncthreads();

    // ---- Phase E: v/u heads. n=0,1 -> V cols h=32wc+16n+t16; n=2,3 -> U same h ----
    #pragma unroll
    for (int m = 0; m < 2; ++m)
        #pragma unroll
        for (int n = 0; n < 4; ++n) acc[m][n] = (f32x4)0.0f;
    {
        const ushort* Vw = wsW + WOFF_V;
        const ushort* Uw = wsW + WOFF_U;
        #pragma unroll
        for (int ks = 0; ks < SD_; ks += 32) {
            int k = ks + g4 * 8;
            short8 a0 = *(const short8*)&Xbuf[swz(32 * wr + t16,      k, 128)];
            short8 a1 = *(const short8*)&Xbuf[swz(32 * wr + 16 + t16, k, 128)];
            #pragma unroll
            for (int n = 0; n < 2; ++n) {
                int h = 32 * wc + 16 * n + t16;
                short8 bv = *(const short8*)&Vw[h * SD_ + k];
                short8 bu = *(const short8*)&Uw[h * SD_ + k];
                acc[0][n]     = __builtin_amdgcn_mfma_f32_16x16x32_bf16(a0, bv, acc[0][n],     0, 0, 0);
                acc[1][n]     = __builtin_amdgcn_mfma_f32_16x16x32_bf16(a1, bv, acc[1][n],     0, 0, 0);
                acc[0][n + 2] = __builtin_amdgcn_mfma_f32_16x16x32_bf16(a0, bu, acc[0][n + 2], 0, 0, 0);
                acc[1][n + 2] = __builtin_amdgcn_mfma_f32_16x16x32_bf16(a1, bu, acc[1][n + 2], 0, 0, 0);
            }
        }
    }

    // ---- score s = sum_h relu(v)*sigmoid(u)*W_w + W_b ----
    #pragma unroll
    for (int m = 0; m < 2; ++m)
        #pragma unroll
        for (int r = 0; r < 4; ++r) {
            float p = 0.0f;
            #pragma unroll
            for (int n = 0; n < 2; ++n) {
                int h = 32 * wc + 16 * n + t16;
                float vv = fmaxf(acc[m][n][r] + V_b[h], 0.0f);
                float uu = sigmoidf_(acc[m][n + 2][r] + U_b[h]);
                p = fmaf(vv * uu, W_w[h], p);
            }
            p += __shfl_xor(p, 1);
            p += __shfl_xor(p, 2);
            p += __shfl_xor(p, 4);
            p += __shfl_xor(p, 8);
            if (t16 == 0) sP[wc][32 * wr + 16 * m + 4 * g4 + r] = p;
        }
    __syncthreads();
    if (tid < 128) {
        float s = sP[0][tid] + sP[1][tid] + W_b[0];
        sS[tid] = s;
        s_out[(size_t)b * N_ + tok0 + tid] = s;
    }
    __syncthreads();

    // ---- Phase F: zpart[k] = sum_t s[t] * ffeat[t][k] ----
    {
        int k = tid & 127, q = tid >> 7;
        float z = 0.0f;
        #pragma unroll
        for (int t = 0; t < 32; ++t) {
            int row = q * 32 + t;
            z = fmaf(sS[row], bf2f(Xbuf[swz(row, k, 128)]), z);
        }
        zq[q][k] = z;
    }
    __syncthreads();
    if (tid < 128)
        zpart[(size_t)bx * 128 + tid] = zq[0][tid] + zq[1][tid] + zq[2][tid] + zq[3][tid];
}

// Grid: 32 blocks, 128 threads.
__global__ __launch_bounds__(128)
void reduce_logits(const float* __restrict__ zpart,
                   const float* __restrict__ cls_w, const float* __restrict__ cls_b,
                   float* __restrict__ out)
{
    __shared__ float sZ[128];
    int b = blockIdx.x, k = threadIdx.x;
    float z = 0.0f;
    #pragma unroll
    for (int t = 0; t < 16; ++t) z += zpart[(size_t)(b * 16 + t) * 128 + k];
    sZ[k] = z;
    __syncthreads();
    if (k < 2) {
        float acc = cls_b[k];
        for (int i = 0; i < 128; ++i) acc = fmaf(sZ[i], cls_w[k * 128 + i], acc);
        out[(size_t)B_ * N_ + b * 2 + k] = acc;
    }
}

extern "C" void kernel_launch(void* const* d_in, const int* in_sizes, int n_in,
                              void* d_out, int out_size, void* d_ws, size_t ws_size,
                              hipStream_t stream) {
    const float* vfeat = (const float*)d_in[0];
    const float* afeat = (const float*)d_in[1];
    const float* vfc_w = (const float*)d_in[2];
    const float* vfc_b = (const float*)d_in[3];
    const float* afc_w = (const float*)d_in[4];
    const float* afc_b = (const float*)d_in[5];
    const float* am_w  = (const float*)d_in[6];
    const float* am_b  = (const float*)d_in[7];
    const float* U_w   = (const float*)d_in[8];
    const float* U_b   = (const float*)d_in[9];
    const float* V_w   = (const float*)d_in[10];
    const float* V_b   = (const float*)d_in[11];
    const float* W_w   = (const float*)d_in[12];
    const float* W_b   = (const float*)d_in[13];
    const float* cls_w = (const float*)d_in[14];
    const float* cls_b = (const float*)d_in[15];

    float* out   = (float*)d_out;
    ushort* wsW  = (ushort*)d_ws;                           // 229376 B of bf16 weights
    float* zpart = (float*)((char*)d_ws + (size_t)WTOT * 2); // 512*128*4 = 256 KB

    cvt_weights<<<dim3(WTOT / 1024), dim3(256), 0, stream>>>(vfc_w, afc_w, am_w, V_w, U_w, wsW);
    fused_mil<<<dim3(B_ * 16), dim3(THREADS), 0, stream>>>(
        vfeat, afeat, wsW, afc_b, am_b, vfc_b, V_b, U_b, W_w, W_b, out, zpart);
    reduce_logits<<<dim3(B_), dim3(128), 0, stream>>>(zpart, cls_w, cls_b, out);
}

// Round 4
// 75.493 us; speedup vs baseline: 1.4314x; 1.4314x over previous
//
#include <hip/hip_runtime.h>
#include <hip/hip_bf16.h>

#define B_   32
#define N_   2048
#define VD_  512
#define AD_  128
#define SD_  128
#define TM   128
#define THREADS 512

typedef __attribute__((ext_vector_type(8))) short short8;
typedef __attribute__((ext_vector_type(4))) float f32x4;

// ws layout (ushort element offsets) for fragment-packed bf16 weights.
// Packing: for W[C][K], frag (n,kc,l=g4*16+tc,e): dst[((n*(K/32)+kc)*64+l)*8+e] = W[n*16+tc][kc*32+g4*8+e]
// => a wave's B-load for (ntile,kc) is 64 lanes x 16B fully contiguous (1KB).
#define WOFF_VFC 0        // C=128,K=512: 65536
#define WOFF_AFC 65536    // C=128,K=128: 16384
#define WOFF_AM  81920    // C=128,K=128: 16384
#define WOFF_V   98304    // C=64, K=128: 8192
#define WOFF_U   106496   // C=64, K=128: 8192
#define WTOT     114688   // ushorts = 229376 bytes; zpart follows

__device__ __forceinline__ float sigmoidf_(float x) { return 1.0f / (1.0f + __expf(-x)); }

__device__ __forceinline__ ushort f2bf(float x) {   // RNE
    union { float f; unsigned int i; } v; v.f = x;
    unsigned int r = v.i + 0x7FFFu + ((v.i >> 16) & 1u);
    return (ushort)(r >> 16);
}
__device__ __forceinline__ float bf2f(ushort u) {
    union { unsigned int i; float f; } v; v.i = ((unsigned int)u) << 16; return v.f;
}
// Swizzled elem index into row-major [R][128] ushort LDS tile (keeps 16B chunks intact)
__device__ __forceinline__ int swz(int row, int k, int ldk) {
    return row * ldk + (k ^ ((row & 7) << 3));
}
__device__ __forceinline__ short8 pack8(float4 x, float4 y) {
    short8 r;
    r[0] = (short)f2bf(x.x); r[1] = (short)f2bf(x.y); r[2] = (short)f2bf(x.z); r[3] = (short)f2bf(x.w);
    r[4] = (short)f2bf(y.x); r[5] = (short)f2bf(y.y); r[6] = (short)f2bf(y.z); r[7] = (short)f2bf(y.w);
    return r;
}

// ---- weight pre-conversion + fragment packing (one fragment per thread) ----
__global__ __launch_bounds__(256)
void cvt_weights(const float* __restrict__ vfc, const float* __restrict__ afc,
                 const float* __restrict__ am,  const float* __restrict__ Vw,
                 const float* __restrict__ Uw,  ushort* __restrict__ dst)
{
    int f = blockIdx.x * 256 + threadIdx.x;        // fragment id, WTOT/8 = 14336 total
    if (f >= WTOT / 8) return;
    int e0 = f * 8;
    const float* src; int base, K;
    if      (e0 < WOFF_AFC) { src = vfc; base = WOFF_VFC; K = 512; }
    else if (e0 < WOFF_AM)  { src = afc; base = WOFF_AFC; K = 128; }
    else if (e0 < WOFF_V)   { src = am;  base = WOFF_AM;  K = 128; }
    else if (e0 < WOFF_U)   { src = Vw;  base = WOFF_V;   K = 128; }
    else                    { src = Uw;  base = WOFF_U;   K = 128; }
    int lf = f - base / 8;
    int l = lf & 63, rem = lf >> 6;
    int NK = K / 32;
    int kc = rem % NK, n = rem / NK;
    int tc = l & 15, g4 = l >> 4;
    const float* sp = src + (size_t)(n * 16 + tc) * K + kc * 32 + g4 * 8;
    float4 x = ((const float4*)sp)[0], y = ((const float4*)sp)[1];
    short8 o = pack8(x, y);
    *(short8*)(dst + e0) = o;
}

// GEMM, A from global f32 (cvt in-reg), B fragment-packed global bf16.
// Software-pipelined depth 1: next-step A/B loads issued before current MFMAs.
template<int K>
__device__ __forceinline__ void gemm_gp(const float* __restrict__ A,     // tile base, ld=K
                                        const ushort* __restrict__ Bp,   // packed, this matrix
                                        int wr, int wc, int t16, int g4, int lane,
                                        f32x4 (&acc)[2][4])
{
    constexpr int NK = K / 32;
    const float* a0p = A + (size_t)(32 * wr + t16) * K + g4 * 8;
    const float* a1p = A + (size_t)(32 * wr + 16 + t16) * K + g4 * 8;
    const ushort* bp = Bp + (size_t)(4 * wc) * NK * 512 + lane * 8;

    float4 pa[4]; short8 pb[4];
    pa[0] = ((const float4*)a0p)[0]; pa[1] = ((const float4*)a0p)[1];
    pa[2] = ((const float4*)a1p)[0]; pa[3] = ((const float4*)a1p)[1];
    #pragma unroll
    for (int n = 0; n < 4; ++n) pb[n] = *(const short8*)(bp + n * NK * 512);

    #pragma unroll
    for (int kc = 0; kc < NK; ++kc) {
        short8 a0 = pack8(pa[0], pa[1]);
        short8 a1 = pack8(pa[2], pa[3]);
        short8 b0 = pb[0], b1 = pb[1], b2 = pb[2], b3 = pb[3];
        if (kc + 1 < NK) {
            const float* na0 = a0p + (kc + 1) * 32;
            const float* na1 = a1p + (kc + 1) * 32;
            pa[0] = ((const float4*)na0)[0]; pa[1] = ((const float4*)na0)[1];
            pa[2] = ((const float4*)na1)[0]; pa[3] = ((const float4*)na1)[1];
            #pragma unroll
            for (int n = 0; n < 4; ++n)
                pb[n] = *(const short8*)(bp + (kc + 1) * 512 + n * NK * 512);
        }
        acc[0][0] = __builtin_amdgcn_mfma_f32_16x16x32_bf16(a0, b0, acc[0][0], 0, 0, 0);
        acc[1][0] = __builtin_amdgcn_mfma_f32_16x16x32_bf16(a1, b0, acc[1][0], 0, 0, 0);
        acc[0][1] = __builtin_amdgcn_mfma_f32_16x16x32_bf16(a0, b1, acc[0][1], 0, 0, 0);
        acc[1][1] = __builtin_amdgcn_mfma_f32_16x16x32_bf16(a1, b1, acc[1][1], 0, 0, 0);
        acc[0][2] = __builtin_amdgcn_mfma_f32_16x16x32_bf16(a0, b2, acc[0][2], 0, 0, 0);
        acc[1][2] = __builtin_amdgcn_mfma_f32_16x16x32_bf16(a1, b2, acc[1][2], 0, 0, 0);
        acc[0][3] = __builtin_amdgcn_mfma_f32_16x16x32_bf16(a0, b3, acc[0][3], 0, 0, 0);
        acc[1][3] = __builtin_amdgcn_mfma_f32_16x16x32_bf16(a1, b3, acc[1][3], 0, 0, 0);
    }
}

// GEMM, A from swizzled LDS bf16, B fragment-packed global bf16 (B prefetched).
template<int K>
__device__ __forceinline__ void gemm_lp(const ushort* __restrict__ Ab,   // LDS [128][128] swz
                                        const ushort* __restrict__ Bp,
                                        int wr, int wc, int t16, int g4, int lane,
                                        f32x4 (&acc)[2][4])
{
    constexpr int NK = K / 32;
    const ushort* bp = Bp + (size_t)(4 * wc) * NK * 512 + lane * 8;
    short8 pb[4];
    #pragma unroll
    for (int n = 0; n < 4; ++n) pb[n] = *(const short8*)(bp + n * NK * 512);

    #pragma unroll
    for (int kc = 0; kc < NK; ++kc) {
        int k = kc * 32 + g4 * 8;
        short8 a0 = *(const short8*)&Ab[swz(32 * wr + t16,      k, 128)];
        short8 a1 = *(const short8*)&Ab[swz(32 * wr + 16 + t16, k, 128)];
        short8 b0 = pb[0], b1 = pb[1], b2 = pb[2], b3 = pb[3];
        if (kc + 1 < NK) {
            #pragma unroll
            for (int n = 0; n < 4; ++n)
                pb[n] = *(const short8*)(bp + (kc + 1) * 512 + n * NK * 512);
        }
        acc[0][0] = __builtin_amdgcn_mfma_f32_16x16x32_bf16(a0, b0, acc[0][0], 0, 0, 0);
        acc[1][0] = __builtin_amdgcn_mfma_f32_16x16x32_bf16(a1, b0, acc[1][0], 0, 0, 0);
        acc[0][1] = __builtin_amdgcn_mfma_f32_16x16x32_bf16(a0, b1, acc[0][1], 0, 0, 0);
        acc[1][1] = __builtin_amdgcn_mfma_f32_16x16x32_bf16(a1, b1, acc[1][1], 0, 0, 0);
        acc[0][2] = __builtin_amdgcn_mfma_f32_16x16x32_bf16(a0, b2, acc[0][2], 0, 0, 0);
        acc[1][2] = __builtin_amdgcn_mfma_f32_16x16x32_bf16(a1, b2, acc[1][2], 0, 0, 0);
        acc[0][3] = __builtin_amdgcn_mfma_f32_16x16x32_bf16(a0, b3, acc[0][3], 0, 0, 0);
        acc[1][3] = __builtin_amdgcn_mfma_f32_16x16x32_bf16(a1, b3, acc[1][3], 0, 0, 0);
    }
}

// Grid: 32 b x 16 tiles = 512 blocks, 512 threads (8 waves). LDS ~35.5KB -> 2 blocks/CU.
__global__ __launch_bounds__(THREADS, 4)
void fused_mil(const float* __restrict__ vfeat, const float* __restrict__ afeat,
               const ushort* __restrict__ wsW,
               const float* __restrict__ afc_b, const float* __restrict__ am_b,
               const float* __restrict__ vfc_b,
               const float* __restrict__ V_b,   const float* __restrict__ U_b,
               const float* __restrict__ W_w,   const float* __restrict__ W_b,
               float* __restrict__ s_out, float* __restrict__ zpart)
{
    __shared__ __align__(16) ushort Xbuf[128 * 128];  // ax -> gate -> ffeat (aliased)
    __shared__ float sP[2][128];
    __shared__ float sS[128];
    __shared__ float zq[4][128];

    const int tid  = threadIdx.x;
    const int bx   = blockIdx.x;
    const int b    = bx >> 4;
    const int tok0 = (bx & 15) * TM;
    const int wid  = tid >> 6;
    const int lane = tid & 63;
    const int t16  = lane & 15;
    const int g4   = lane >> 4;
    const int wr   = wid >> 1;
    const int wc   = wid & 1;

    f32x4 acc[2][4];

    // ---- Phase A: ax = relu(afeat @ afc_w^T + afc_b) -> Xbuf ----
    #pragma unroll
    for (int m = 0; m < 2; ++m)
        #pragma unroll
        for (int n = 0; n < 4; ++n) acc[m][n] = (f32x4)0.0f;
    gemm_gp<AD_>(afeat + ((size_t)b * N_ + tok0) * AD_, wsW + WOFF_AFC, wr, wc, t16, g4, lane, acc);
    #pragma unroll
    for (int n = 0; n < 4; ++n) {
        int c = 64 * wc + 16 * n + t16;
        float bias = afc_b[c];
        #pragma unroll
        for (int m = 0; m < 2; ++m)
            #pragma unroll
            for (int r = 0; r < 4; ++r) {
                int row = 32 * wr + 16 * m + 4 * g4 + r;
                Xbuf[swz(row, c, 128)] = f2bf(fmaxf(acc[m][n][r] + bias, 0.0f));
            }
    }
    __syncthreads();

    // ---- Phase B: gate = sigmoid(ax @ am_w^T + am_b), stashed bf16 into Xbuf ----
    #pragma unroll
    for (int m = 0; m < 2; ++m)
        #pragma unroll
        for (int n = 0; n < 4; ++n) acc[m][n] = (f32x4)0.0f;
    gemm_lp<SD_>(Xbuf, wsW + WOFF_AM, wr, wc, t16, g4, lane, acc);
    __syncthreads();   // everyone done reading ax
    #pragma unroll
    for (int n = 0; n < 4; ++n) {
        int c = 64 * wc + 16 * n + t16;
        float bias = am_b[c];
        #pragma unroll
        for (int m = 0; m < 2; ++m)
            #pragma unroll
            for (int r = 0; r < 4; ++r) {
                int row = 32 * wr + 16 * m + 4 * g4 + r;
                Xbuf[swz(row, c, 128)] = f2bf(sigmoidf_(acc[m][n][r] + bias));
            }
    }
    // no barrier: phase C reads no LDS; gate cells are thread-private

    // ---- Phase C: vo1 = vfeat @ vfc_w^T (K=512, barrier-free, pipelined) ----
    #pragma unroll
    for (int m = 0; m < 2; ++m)
        #pragma unroll
        for (int n = 0; n < 4; ++n) acc[m][n] = (f32x4)0.0f;
    gemm_gp<VD_>(vfeat + ((size_t)b * N_ + tok0) * VD_, wsW + WOFF_VFC, wr, wc, t16, g4, lane, acc);

    // epilogue: ffeat = relu(vo1+b) * (1 + gate) -> Xbuf (thread-private cells)
    #pragma unroll
    for (int n = 0; n < 4; ++n) {
        int c = 64 * wc + 16 * n + t16;
        float vb = vfc_b[c];
        #pragma unroll
        for (int m = 0; m < 2; ++m)
            #pragma unroll
            for (int r = 0; r < 4; ++r) {
                int row = 32 * wr + 16 * m + 4 * g4 + r;
                float g   = bf2f(Xbuf[swz(row, c, 128)]);
                float vo1 = fmaxf(acc[m][n][r] + vb, 0.0f);
                Xbuf[swz(row, c, 128)] = f2bf(vo1 * (1.0f + g));
            }
    }
    __syncthreads();

    // ---- Phase E: v/u heads. n=0,1: V tiles 2wc+n; n=2,3: U tiles 2wc+(n-2).
    //      Result col h = 32*wc + 16*(n&1) + t16 for both halves. ----
    #pragma unroll
    for (int m = 0; m < 2; ++m)
        #pragma unroll
        for (int n = 0; n < 4; ++n) acc[m][n] = (f32x4)0.0f;
    {
        const ushort* Vp = wsW + WOFF_V;   // C=64,K=128 -> NK=4, per-tile 4*512
        const ushort* Up = wsW + WOFF_U;
        short8 pb[4];
        pb[0] = *(const short8*)(Vp + ((size_t)(2 * wc + 0) * 4 + 0) * 512 + lane * 8);
        pb[1] = *(const short8*)(Vp + ((size_t)(2 * wc + 1) * 4 + 0) * 512 + lane * 8);
        pb[2] = *(const short8*)(Up + ((size_t)(2 * wc + 0) * 4 + 0) * 512 + lane * 8);
        pb[3] = *(const short8*)(Up + ((size_t)(2 * wc + 1) * 4 + 0) * 512 + lane * 8);
        #pragma unroll
        for (int kc = 0; kc < 4; ++kc) {
            int k = kc * 32 + g4 * 8;
            short8 a0 = *(const short8*)&Xbuf[swz(32 * wr + t16,      k, 128)];
            short8 a1 = *(const short8*)&Xbuf[swz(32 * wr + 16 + t16, k, 128)];
            short8 b0 = pb[0], b1 = pb[1], b2 = pb[2], b3 = pb[3];
            if (kc < 3) {
                pb[0] = *(const short8*)(Vp + ((size_t)(2 * wc + 0) * 4 + kc + 1) * 512 + lane * 8);
                pb[1] = *(const short8*)(Vp + ((size_t)(2 * wc + 1) * 4 + kc + 1) * 512 + lane * 8);
                pb[2] = *(const short8*)(Up + ((size_t)(2 * wc + 0) * 4 + kc + 1) * 512 + lane * 8);
                pb[3] = *(const short8*)(Up + ((size_t)(2 * wc + 1) * 4 + kc + 1) * 512 + lane * 8);
            }
            acc[0][0] = __builtin_amdgcn_mfma_f32_16x16x32_bf16(a0, b0, acc[0][0], 0, 0, 0);
            acc[1][0] = __builtin_amdgcn_mfma_f32_16x16x32_bf16(a1, b0, acc[1][0], 0, 0, 0);
            acc[0][1] = __builtin_amdgcn_mfma_f32_16x16x32_bf16(a0, b1, acc[0][1], 0, 0, 0);
            acc[1][1] = __builtin_amdgcn_mfma_f32_16x16x32_bf16(a1, b1, acc[1][1], 0, 0, 0);
            acc[0][2] = __builtin_amdgcn_mfma_f32_16x16x32_bf16(a0, b2, acc[0][2], 0, 0, 0);
            acc[1][2] = __builtin_amdgcn_mfma_f32_16x16x32_bf16(a1, b2, acc[1][2], 0, 0, 0);
            acc[0][3] = __builtin_amdgcn_mfma_f32_16x16x32_bf16(a0, b3, acc[0][3], 0, 0, 0);
            acc[1][3] = __builtin_amdgcn_mfma_f32_16x16x32_bf16(a1, b3, acc[1][3], 0, 0, 0);
        }
    }

    // ---- score s = sum_h relu(v)*sigmoid(u)*W_w + W_b ----
    #pragma unroll
    for (int m = 0; m < 2; ++m)
        #pragma unroll
        for (int r = 0; r < 4; ++r) {
            float p = 0.0f;
            #pragma unroll
            for (int n = 0; n < 2; ++n) {
                int h = 32 * wc + 16 * n + t16;
                float vv = fmaxf(acc[m][n][r] + V_b[h], 0.0f);
                float uu = sigmoidf_(acc[m][n + 2][r] + U_b[h]);
                p = fmaf(vv * uu, W_w[h], p);
            }
            p += __shfl_xor(p, 1);
            p += __shfl_xor(p, 2);
            p += __shfl_xor(p, 4);
            p += __shfl_xor(p, 8);
            if (t16 == 0) sP[wc][32 * wr + 16 * m + 4 * g4 + r] = p;
        }
    __syncthreads();
    if (tid < 128) {
        float s = sP[0][tid] + sP[1][tid] + W_b[0];
        sS[tid] = s;
        s_out[(size_t)b * N_ + tok0 + tid] = s;
    }
    __syncthreads();

    // ---- Phase F: zpart[k] = sum_t s[t] * ffeat[t][k] ----
    {
        int k = tid & 127, q = tid >> 7;
        float z = 0.0f;
        #pragma unroll
        for (int t = 0; t < 32; ++t) {
            int row = q * 32 + t;
            z = fmaf(sS[row], bf2f(Xbuf[swz(row, k, 128)]), z);
        }
        zq[q][k] = z;
    }
    __syncthreads();
    if (tid < 128)
        zpart[(size_t)bx * 128 + tid] = zq[0][tid] + zq[1][tid] + zq[2][tid] + zq[3][tid];
}

// Grid: 32 blocks, 128 threads.
__global__ __launch_bounds__(128)
void reduce_logits(const float* __restrict__ zpart,
                   const float* __restrict__ cls_w, const float* __restrict__ cls_b,
                   float* __restrict__ out)
{
    __shared__ float sZ[128];
    int b = blockIdx.x, k = threadIdx.x;
    float z = 0.0f;
    #pragma unroll
    for (int t = 0; t < 16; ++t) z += zpart[(size_t)(b * 16 + t) * 128 + k];
    sZ[k] = z;
    __syncthreads();
    if (k < 2) {
        float acc = cls_b[k];
        for (int i = 0; i < 128; ++i) acc = fmaf(sZ[i], cls_w[k * 128 + i], acc);
        out[(size_t)B_ * N_ + b * 2 + k] = acc;
    }
}

extern "C" void kernel_launch(void* const* d_in, const int* in_sizes, int n_in,
                              void* d_out, int out_size, void* d_ws, size_t ws_size,
                              hipStream_t stream) {
    const float* vfeat = (const float*)d_in[0];
    const float* afeat = (const float*)d_in[1];
    const float* vfc_w = (const float*)d_in[2];
    const float* vfc_b = (const float*)d_in[3];
    const float* afc_w = (const float*)d_in[4];
    const float* afc_b = (const float*)d_in[5];
    const float* am_w  = (const float*)d_in[6];
    const float* am_b  = (const float*)d_in[7];
    const float* U_w   = (const float*)d_in[8];
    const float* U_b   = (const float*)d_in[9];
    const float* V_w   = (const float*)d_in[10];
    const float* V_b   = (const float*)d_in[11];
    const float* W_w   = (const float*)d_in[12];
    const float* W_b   = (const float*)d_in[13];
    const float* cls_w = (const float*)d_in[14];
    const float* cls_b = (const float*)d_in[15];

    float* out   = (float*)d_out;
    ushort* wsW  = (ushort*)d_ws;                            // 229376 B packed bf16 weights
    float* zpart = (float*)((char*)d_ws + (size_t)WTOT * 2); // 512*128*4 = 256 KB

    cvt_weights<<<dim3((WTOT / 8 + 255) / 256), dim3(256), 0, stream>>>(vfc_w, afc_w, am_w, V_w, U_w, wsW);
    fused_mil<<<dim3(B_ * 16), dim3(THREADS), 0, stream>>>(
        vfeat, afeat, wsW, afc_b, am_b, vfc_b, V_b, U_b, W_w, W_b, out, zpart);
    reduce_logits<<<dim3(B_), dim3(128), 0, stream>>>(zpart, cls_w, cls_b, out);
}

// Round 5
// 52.032 us; speedup vs baseline: 2.0768x; 1.4509x over previous
//
#include <hip/hip_runtime.h>
#include <hip/hip_bf16.h>

#define B_   32
#define N_   2048
#define VD_  512
#define AD_  128
#define SD_  128
#define TM   128
#define THREADS 512

typedef __attribute__((ext_vector_type(8))) short short8;
typedef __attribute__((ext_vector_type(4))) float f32x4;

// ws layout (ushort element offsets) for fragment-packed bf16 weights.
// Packing: for W[C][K], frag (n,kc,l,e): dst[((n*(K/32)+kc)*64+l)*8+e] = W[n*16+(l&15)][kc*32+(l>>4)*8+e]
#define WOFF_VFC 0        // C=128,K=512: 65536
#define WOFF_AFC 65536    // C=128,K=128: 16384
#define WOFF_AM  81920    // C=128,K=128: 16384
#define WOFF_V   98304    // C=64, K=128: 8192
#define WOFF_U   106496   // C=64, K=128: 8192
#define WTOT     114688   // ushorts = 229376 bytes; zpart follows

__device__ __forceinline__ float sigmoidf_(float x) { return 1.0f / (1.0f + __expf(-x)); }

__device__ __forceinline__ ushort f2bf(float x) {   // RNE
    union { float f; unsigned int i; } v; v.f = x;
    unsigned int r = v.i + 0x7FFFu + ((v.i >> 16) & 1u);
    return (ushort)(r >> 16);
}
__device__ __forceinline__ float bf2f(ushort u) {
    union { unsigned int i; float f; } v; v.i = ((unsigned int)u) << 16; return v.f;
}
// Xbuf swizzle: ushort [128][128], XOR on 16B chunks
__device__ __forceinline__ int swz(int row, int k, int ldk) {
    return row * ldk + (k ^ ((row & 7) << 3));
}
// Abuf swizzle: f32 [128][32], (row, 16B-chunk c) -> f32 index
__device__ __forceinline__ int fswz(int row, int c) {
    return row * 32 + ((c ^ (row & 7)) << 2);
}
__device__ __forceinline__ short8 pack8(float4 x, float4 y) {
    short8 r;
    r[0] = (short)f2bf(x.x); r[1] = (short)f2bf(x.y); r[2] = (short)f2bf(x.z); r[3] = (short)f2bf(x.w);
    r[4] = (short)f2bf(y.x); r[5] = (short)f2bf(y.y); r[6] = (short)f2bf(y.z); r[7] = (short)f2bf(y.w);
    return r;
}

// Stage one [128][32]-f32 K-chunk (16KB) via global_load_lds, linear LDS dest,
// inverse-swizzled global source (so swizzled reads see the right data).
__device__ __forceinline__ void stage_tile32(const float* __restrict__ src, int ldK, int kcol,
                                             float* lds_base, int wid, int lane)
{
    #pragma unroll
    for (int i = 0; i < 2; ++i) {
        int D   = i * 512 + wid * 64 + lane;          // 16B-chunk id, 0..1023
        int row = D >> 3, jj = D & 7;
        int j   = jj ^ (row & 7);                     // source chunk for this slot
        const float* gp = src + (size_t)row * ldK + kcol + j * 4;
        float* lp = lds_base + (size_t)(i * 512 + wid * 64) * 4;  // wave-uniform base
        __builtin_amdgcn_global_load_lds((const __attribute__((address_space(1))) void*)gp,
                                         (__attribute__((address_space(3))) void*)lp, 16, 0, 0);
    }
}

// ---- weight pre-conversion + fragment packing ----
__global__ __launch_bounds__(256)
void cvt_weights(const float* __restrict__ vfc, const float* __restrict__ afc,
                 const float* __restrict__ am,  const float* __restrict__ Vw,
                 const float* __restrict__ Uw,  ushort* __restrict__ dst)
{
    int f = blockIdx.x * 256 + threadIdx.x;        // fragment id, WTOT/8 total
    if (f >= WTOT / 8) return;
    int e0 = f * 8;
    const float* src; int base, K;
    if      (e0 < WOFF_AFC) { src = vfc; base = WOFF_VFC; K = 512; }
    else if (e0 < WOFF_AM)  { src = afc; base = WOFF_AFC; K = 128; }
    else if (e0 < WOFF_V)   { src = am;  base = WOFF_AM;  K = 128; }
    else if (e0 < WOFF_U)   { src = Vw;  base = WOFF_V;   K = 128; }
    else                    { src = Uw;  base = WOFF_U;   K = 128; }
    int lf = f - base / 8;
    int l = lf & 63, rem = lf >> 6;
    int NK = K / 32;
    int kc = rem % NK, n = rem / NK;
    int tc = l & 15, g4 = l >> 4;
    const float* sp = src + (size_t)(n * 16 + tc) * K + kc * 32 + g4 * 8;
    float4 x = ((const float4*)sp)[0], y = ((const float4*)sp)[1];
    short8 o = pack8(x, y);
    *(short8*)(dst + e0) = o;
}

// Staged GEMM: A from global f32 via global_load_lds double-buffer (chunk0 pre-issued
// by caller into Ab0), B fragment-packed global bf16 with depth-1 reg prefetch.
template<int K>
__device__ __forceinline__ void gemm_staged(const float* __restrict__ Asrc,   // tile base, ld=K
                                            const ushort* __restrict__ Bp,
                                            float* Ab0, float* Ab1,
                                            int wid, int lane, int wr, int wc, int t16, int g4,
                                            f32x4 (&acc)[2][4])
{
    constexpr int NC = K / 32;
    const ushort* bp = Bp + (size_t)(4 * wc) * NC * 512 + lane * 8;
    short8 pb[4];
    #pragma unroll
    for (int n = 0; n < 4; ++n) pb[n] = *(const short8*)(bp + (size_t)n * NC * 512);

    #pragma unroll
    for (int kc = 0; kc < NC; ++kc) {
        float* cur = (kc & 1) ? Ab1 : Ab0;
        float* nxt = (kc & 1) ? Ab0 : Ab1;
        __syncthreads();                         // chunk kc arrived; prev readers of nxt done
        if (kc + 1 < NC) stage_tile32(Asrc, K, (kc + 1) * 32, nxt, wid, lane);
        int row0 = 32 * wr + t16, row1 = row0 + 16;
        float4 x0 = *(const float4*)&cur[fswz(row0, 2 * g4)];
        float4 y0 = *(const float4*)&cur[fswz(row0, 2 * g4 + 1)];
        float4 x1 = *(const float4*)&cur[fswz(row1, 2 * g4)];
        float4 y1 = *(const float4*)&cur[fswz(row1, 2 * g4 + 1)];
        short8 a0 = pack8(x0, y0), a1 = pack8(x1, y1);
        short8 b0 = pb[0], b1 = pb[1], b2 = pb[2], b3 = pb[3];
        if (kc + 1 < NC) {
            #pragma unroll
            for (int n = 0; n < 4; ++n)
                pb[n] = *(const short8*)(bp + (size_t)(kc + 1) * 512 + (size_t)n * NC * 512);
        }
        acc[0][0] = __builtin_amdgcn_mfma_f32_16x16x32_bf16(a0, b0, acc[0][0], 0, 0, 0);
        acc[1][0] = __builtin_amdgcn_mfma_f32_16x16x32_bf16(a1, b0, acc[1][0], 0, 0, 0);
        acc[0][1] = __builtin_amdgcn_mfma_f32_16x16x32_bf16(a0, b1, acc[0][1], 0, 0, 0);
        acc[1][1] = __builtin_amdgcn_mfma_f32_16x16x32_bf16(a1, b1, acc[1][1], 0, 0, 0);
        acc[0][2] = __builtin_amdgcn_mfma_f32_16x16x32_bf16(a0, b2, acc[0][2], 0, 0, 0);
        acc[1][2] = __builtin_amdgcn_mfma_f32_16x16x32_bf16(a1, b2, acc[1][2], 0, 0, 0);
        acc[0][3] = __builtin_amdgcn_mfma_f32_16x16x32_bf16(a0, b3, acc[0][3], 0, 0, 0);
        acc[1][3] = __builtin_amdgcn_mfma_f32_16x16x32_bf16(a1, b3, acc[1][3], 0, 0, 0);
    }
}

// GEMM with A from swizzled LDS bf16 (Xbuf), B fragment-packed global.
template<int K>
__device__ __forceinline__ void gemm_lp(const ushort* __restrict__ Ab,
                                        const ushort* __restrict__ Bp,
                                        int wr, int wc, int t16, int g4, int lane,
                                        f32x4 (&acc)[2][4])
{
    constexpr int NK = K / 32;
    const ushort* bp = Bp + (size_t)(4 * wc) * NK * 512 + lane * 8;
    short8 pb[4];
    #pragma unroll
    for (int n = 0; n < 4; ++n) pb[n] = *(const short8*)(bp + (size_t)n * NK * 512);

    #pragma unroll
    for (int kc = 0; kc < NK; ++kc) {
        int k = kc * 32 + g4 * 8;
        short8 a0 = *(const short8*)&Ab[swz(32 * wr + t16,      k, 128)];
        short8 a1 = *(const short8*)&Ab[swz(32 * wr + 16 + t16, k, 128)];
        short8 b0 = pb[0], b1 = pb[1], b2 = pb[2], b3 = pb[3];
        if (kc + 1 < NK) {
            #pragma unroll
            for (int n = 0; n < 4; ++n)
                pb[n] = *(const short8*)(bp + (size_t)(kc + 1) * 512 + (size_t)n * NK * 512);
        }
        acc[0][0] = __builtin_amdgcn_mfma_f32_16x16x32_bf16(a0, b0, acc[0][0], 0, 0, 0);
        acc[1][0] = __builtin_amdgcn_mfma_f32_16x16x32_bf16(a1, b0, acc[1][0], 0, 0, 0);
        acc[0][1] = __builtin_amdgcn_mfma_f32_16x16x32_bf16(a0, b1, acc[0][1], 0, 0, 0);
        acc[1][1] = __builtin_amdgcn_mfma_f32_16x16x32_bf16(a1, b1, acc[1][1], 0, 0, 0);
        acc[0][2] = __builtin_amdgcn_mfma_f32_16x16x32_bf16(a0, b2, acc[0][2], 0, 0, 0);
        acc[1][2] = __builtin_amdgcn_mfma_f32_16x16x32_bf16(a1, b2, acc[1][2], 0, 0, 0);
        acc[0][3] = __builtin_amdgcn_mfma_f32_16x16x32_bf16(a0, b3, acc[0][3], 0, 0, 0);
        acc[1][3] = __builtin_amdgcn_mfma_f32_16x16x32_bf16(a1, b3, acc[1][3], 0, 0, 0);
    }
}

// Grid: 32 b x 16 tiles = 512 blocks, 512 threads (8 waves). LDS ~69KB -> 2 blocks/CU.
__global__ __launch_bounds__(THREADS, 4)
void fused_mil(const float* __restrict__ vfeat, const float* __restrict__ afeat,
               const ushort* __restrict__ wsW,
               const float* __restrict__ afc_b, const float* __restrict__ am_b,
               const float* __restrict__ vfc_b,
               const float* __restrict__ V_b,   const float* __restrict__ U_b,
               const float* __restrict__ W_w,   const float* __restrict__ W_b,
               float* __restrict__ s_out, float* __restrict__ zpart)
{
    __shared__ __align__(16) ushort Xbuf[128 * 128];   // ax -> gate -> ffeat (aliased), 32KB
    __shared__ __align__(16) float  Abuf[2][128 * 32]; // staged A K-chunks, 2x16KB
    __shared__ float sP[2][128];
    __shared__ float sS[128];
    __shared__ float zq[4][128];

    const int tid  = threadIdx.x;
    const int bx   = blockIdx.x;
    const int b    = bx >> 4;
    const int tok0 = (bx & 15) * TM;
    const int wid  = tid >> 6;
    const int lane = tid & 63;
    const int t16  = lane & 15;
    const int g4   = lane >> 4;
    const int wr   = wid >> 1;
    const int wc   = wid & 1;

    const float* afeat_t = afeat + ((size_t)b * N_ + tok0) * AD_;
    const float* vfeat_t = vfeat + ((size_t)b * N_ + tok0) * VD_;

    f32x4 acc[2][4];

    // ---- Phase A: ax = relu(afeat @ afc_w^T + afc_b) -> Xbuf ----
    stage_tile32(afeat_t, AD_, 0, Abuf[0], wid, lane);    // pre-issue chunk0
    #pragma unroll
    for (int m = 0; m < 2; ++m)
        #pragma unroll
        for (int n = 0; n < 4; ++n) acc[m][n] = (f32x4)0.0f;
    gemm_staged<AD_>(afeat_t, wsW + WOFF_AFC, Abuf[0], Abuf[1], wid, lane, wr, wc, t16, g4, acc);
    #pragma unroll
    for (int n = 0; n < 4; ++n) {
        int c = 64 * wc + 16 * n + t16;
        float bias = afc_b[c];
        #pragma unroll
        for (int m = 0; m < 2; ++m)
            #pragma unroll
            for (int r = 0; r < 4; ++r) {
                int row = 32 * wr + 16 * m + 4 * g4 + r;
                Xbuf[swz(row, c, 128)] = f2bf(fmaxf(acc[m][n][r] + bias, 0.0f));
            }
    }
    __syncthreads();                                      // ax ready for all waves

    // pre-issue vfeat chunk0 (flies under phase B; Abuf[0] free: all waves past last read)
    stage_tile32(vfeat_t, VD_, 0, Abuf[0], wid, lane);

    // ---- Phase B: gate = sigmoid(ax @ am_w^T + am_b), stashed bf16 into Xbuf ----
    #pragma unroll
    for (int m = 0; m < 2; ++m)
        #pragma unroll
        for (int n = 0; n < 4; ++n) acc[m][n] = (f32x4)0.0f;
    gemm_lp<SD_>(Xbuf, wsW + WOFF_AM, wr, wc, t16, g4, lane, acc);
    __syncthreads();                                      // everyone done reading ax
    #pragma unroll
    for (int n = 0; n < 4; ++n) {
        int c = 64 * wc + 16 * n + t16;
        float bias = am_b[c];
        #pragma unroll
        for (int m = 0; m < 2; ++m)
            #pragma unroll
            for (int r = 0; r < 4; ++r) {
                int row = 32 * wr + 16 * m + 4 * g4 + r;
                Xbuf[swz(row, c, 128)] = f2bf(sigmoidf_(acc[m][n][r] + bias));
            }
    }
    // no barrier: phase C touches no Xbuf; gate cells thread-private

    // ---- Phase C: vo1 = vfeat @ vfc_w^T (K=512, staged, 1 barrier/chunk) ----
    #pragma unroll
    for (int m = 0; m < 2; ++m)
        #pragma unroll
        for (int n = 0; n < 4; ++n) acc[m][n] = (f32x4)0.0f;
    gemm_staged<VD_>(vfeat_t, wsW + WOFF_VFC, Abuf[0], Abuf[1], wid, lane, wr, wc, t16, g4, acc);

    // epilogue: ffeat = relu(vo1+b) * (1 + gate) -> Xbuf (thread-private cells)
    #pragma unroll
    for (int n = 0; n < 4; ++n) {
        int c = 64 * wc + 16 * n + t16;
        float vb = vfc_b[c];
        #pragma unroll
        for (int m = 0; m < 2; ++m)
            #pragma unroll
            for (int r = 0; r < 4; ++r) {
                int row = 32 * wr + 16 * m + 4 * g4 + r;
                float g   = bf2f(Xbuf[swz(row, c, 128)]);
                float vo1 = fmaxf(acc[m][n][r] + vb, 0.0f);
                Xbuf[swz(row, c, 128)] = f2bf(vo1 * (1.0f + g));
            }
    }
    __syncthreads();

    // ---- Phase E: v/u heads. n=0,1: V tiles 2wc+n; n=2,3: U tiles 2wc+(n-2). ----
    #pragma unroll
    for (int m = 0; m < 2; ++m)
        #pragma unroll
        for (int n = 0; n < 4; ++n) acc[m][n] = (f32x4)0.0f;
    {
        const ushort* Vp = wsW + WOFF_V;   // C=64,K=128 -> NK=4, per-tile 4*512
        const ushort* Up = wsW + WOFF_U;
        short8 pb[4];
        pb[0] = *(const short8*)(Vp + ((size_t)(2 * wc + 0) * 4 + 0) * 512 + lane * 8);
        pb[1] = *(const short8*)(Vp + ((size_t)(2 * wc + 1) * 4 + 0) * 512 + lane * 8);
        pb[2] = *(const short8*)(Up + ((size_t)(2 * wc + 0) * 4 + 0) * 512 + lane * 8);
        pb[3] = *(const short8*)(Up + ((size_t)(2 * wc + 1) * 4 + 0) * 512 + lane * 8);
        #pragma unroll
        for (int kc = 0; kc < 4; ++kc) {
            int k = kc * 32 + g4 * 8;
            short8 a0 = *(const short8*)&Xbuf[swz(32 * wr + t16,      k, 128)];
            short8 a1 = *(const short8*)&Xbuf[swz(32 * wr + 16 + t16, k, 128)];
            short8 b0 = pb[0], b1 = pb[1], b2 = pb[2], b3 = pb[3];
            if (kc < 3) {
                pb[0] = *(const short8*)(Vp + ((size_t)(2 * wc + 0) * 4 + kc + 1) * 512 + lane * 8);
                pb[1] = *(const short8*)(Vp + ((size_t)(2 * wc + 1) * 4 + kc + 1) * 512 + lane * 8);
                pb[2] = *(const short8*)(Up + ((size_t)(2 * wc + 0) * 4 + kc + 1) * 512 + lane * 8);
                pb[3] = *(const short8*)(Up + ((size_t)(2 * wc + 1) * 4 + kc + 1) * 512 + lane * 8);
            }
            acc[0][0] = __builtin_amdgcn_mfma_f32_16x16x32_bf16(a0, b0, acc[0][0], 0, 0, 0);
            acc[1][0] = __builtin_amdgcn_mfma_f32_16x16x32_bf16(a1, b0, acc[1][0], 0, 0, 0);
            acc[0][1] = __builtin_amdgcn_mfma_f32_16x16x32_bf16(a0, b1, acc[0][1], 0, 0, 0);
            acc[1][1] = __builtin_amdgcn_mfma_f32_16x16x32_bf16(a1, b1, acc[1][1], 0, 0, 0);
            acc[0][2] = __builtin_amdgcn_mfma_f32_16x16x32_bf16(a0, b2, acc[0][2], 0, 0, 0);
            acc[1][2] = __builtin_amdgcn_mfma_f32_16x16x32_bf16(a1, b2, acc[1][2], 0, 0, 0);
            acc[0][3] = __builtin_amdgcn_mfma_f32_16x16x32_bf16(a0, b3, acc[0][3], 0, 0, 0);
            acc[1][3] = __builtin_amdgcn_mfma_f32_16x16x32_bf16(a1, b3, acc[1][3], 0, 0, 0);
        }
    }

    // ---- score s = sum_h relu(v)*sigmoid(u)*W_w + W_b ----
    #pragma unroll
    for (int m = 0; m < 2; ++m)
        #pragma unroll
        for (int r = 0; r < 4; ++r) {
            float p = 0.0f;
            #pragma unroll
            for (int n = 0; n < 2; ++n) {
                int h = 32 * wc + 16 * n + t16;
                float vv = fmaxf(acc[m][n][r] + V_b[h], 0.0f);
                float uu = sigmoidf_(acc[m][n + 2][r] + U_b[h]);
                p = fmaf(vv * uu, W_w[h], p);
            }
            p += __shfl_xor(p, 1);
            p += __shfl_xor(p, 2);
            p += __shfl_xor(p, 4);
            p += __shfl_xor(p, 8);
            if (t16 == 0) sP[wc][32 * wr + 16 * m + 4 * g4 + r] = p;
        }
    __syncthreads();
    if (tid < 128) {
        float s = sP[0][tid] + sP[1][tid] + W_b[0];
        sS[tid] = s;
        s_out[(size_t)b * N_ + tok0 + tid] = s;
    }
    __syncthreads();

    // ---- Phase F: zpart[k] = sum_t s[t] * ffeat[t][k] ----
    {
        int k = tid & 127, q = tid >> 7;
        float z = 0.0f;
        #pragma unroll
        for (int t = 0; t < 32; ++t) {
            int row = q * 32 + t;
            z = fmaf(sS[row], bf2f(Xbuf[swz(row, k, 128)]), z);
        }
        zq[q][k] = z;
    }
    __syncthreads();
    if (tid < 128)
        zpart[(size_t)bx * 128 + tid] = zq[0][tid] + zq[1][tid] + zq[2][tid] + zq[3][tid];
}

// Grid: 32 blocks, 128 threads.
__global__ __launch_bounds__(128)
void reduce_logits(const float* __restrict__ zpart,
                   const float* __restrict__ cls_w, const float* __restrict__ cls_b,
                   float* __restrict__ out)
{
    __shared__ float sZ[128];
    int b = blockIdx.x, k = threadIdx.x;
    float z = 0.0f;
    #pragma unroll
    for (int t = 0; t < 16; ++t) z += zpart[(size_t)(b * 16 + t) * 128 + k];
    sZ[k] = z;
    __syncthreads();
    if (k < 2) {
        float acc = cls_b[k];
        for (int i = 0; i < 128; ++i) acc = fmaf(sZ[i], cls_w[k * 128 + i], acc);
        out[(size_t)B_ * N_ + b * 2 + k] = acc;
    }
}

extern "C" void kernel_launch(void* const* d_in, const int* in_sizes, int n_in,
                              void* d_out, int out_size, void* d_ws, size_t ws_size,
                              hipStream_t stream) {
    const float* vfeat = (const float*)d_in[0];
    const float* afeat = (const float*)d_in[1];
    const float* vfc_w = (const float*)d_in[2];
    const float* vfc_b = (const float*)d_in[3];
    const float* afc_w = (const float*)d_in[4];
    const float* afc_b = (const float*)d_in[5];
    const float* am_w  = (const float*)d_in[6];
    const float* am_b  = (const float*)d_in[7];
    const float* U_w   = (const float*)d_in[8];
    const float* U_b   = (const float*)d_in[9];
    const float* V_w   = (const float*)d_in[10];
    const float* V_b   = (const float*)d_in[11];
    const float* W_w   = (const float*)d_in[12];
    const float* W_b   = (const float*)d_in[13];
    const float* cls_w = (const float*)d_in[14];
    const float* cls_b = (const float*)d_in[15];

    float* out   = (float*)d_out;
    ushort* wsW  = (ushort*)d_ws;                            // 229376 B packed bf16 weights
    float* zpart = (float*)((char*)d_ws + (size_t)WTOT * 2); // 512*128*4 = 256 KB

    cvt_weights<<<dim3((WTOT / 8 + 255) / 256), dim3(256), 0, stream>>>(vfc_w, afc_w, am_w, V_w, U_w, wsW);
    fused_mil<<<dim3(B_ * 16), dim3(THREADS), 0, stream>>>(
        vfeat, afeat, wsW, afc_b, am_b, vfc_b, V_b, U_b, W_w, W_b, out, zpart);
    reduce_logits<<<dim3(B_), dim3(128), 0, stream>>>(zpart, cls_w, cls_b, out);
}